// Round 1
// baseline (629.694 us; speedup 1.0000x reference)
//
#include <hip/hip_runtime.h>
#include <hip/hip_bf16.h>

#define D_IN_ 1536
#define D_SC_ 234
#define DM_   64
#define DSN_  8
#define NC_   234
#define T_    12
#define NS_   20
#define B_    4096
#define NROW_ (B_ * T_)       // 49152
#define KPAD_ 1792            // 1770 padded to 56*32
#define LN_EPS_ 1e-5f

typedef __bf16 bf16x8 __attribute__((ext_vector_type(8)));
typedef float  f32x4  __attribute__((ext_vector_type(4)));

// ---------------- prep: pack W_in [1770][64] -> Wt bf16 [64][1792] (zero-padded) ----------
__global__ void prep_w(const float* __restrict__ W_in, unsigned short* __restrict__ Wt) {
    int idx = blockIdx.x * 256 + threadIdx.x;
    if (idx >= 64 * KPAD_) return;
    int n = idx / KPAD_, k = idx - n * KPAD_;
    float v = (k < (D_IN_ + D_SC_)) ? W_in[k * 64 + n] : 0.0f;
    __hip_bfloat16 hb = __float2bfloat16(v);
    Wt[idx] = *reinterpret_cast<unsigned short*>(&hb);
}

// ---------------- prep: meta[b][n] = cat(site_e, hour_e) @ W_meta + b_meta ----------------
__global__ void prep_meta(const int* __restrict__ site_ids, const int* __restrict__ hours,
                          const float* __restrict__ site_emb, const float* __restrict__ hour_emb,
                          const float* __restrict__ W_meta, const float* __restrict__ b_meta,
                          float* __restrict__ meta) {
    int idx = blockIdx.x * 256 + threadIdx.x;
    if (idx >= B_ * 64) return;
    int b = idx >> 6, n = idx & 63;
    int s = min(max(site_ids[b], 0), NS_ - 1);
    int h = min(max(hours[b], 0), 23);
    float acc = b_meta[n];
#pragma unroll
    for (int k = 0; k < 8; k++) acc += site_emb[s * 8 + k] * W_meta[k * 64 + n];
#pragma unroll
    for (int k = 0; k < 8; k++) acc += hour_emb[h * 8 + k] * W_meta[(8 + k) * 64 + n];
    meta[idx] = acc;
}

// ---------------- K1: [49152,1792]bf16 @ [1792,64]bf16 MFMA + bias + LN + gelu + meta + pos
__launch_bounds__(256)
__global__ void k1_gemm(const float* __restrict__ emb, const float* __restrict__ scores,
                        const unsigned short* __restrict__ Wt,
                        const float* __restrict__ b_in, const float* __restrict__ ln_in_g,
                        const float* __restrict__ ln_in_b, const float* __restrict__ meta,
                        const float* __restrict__ pos_enc, float* __restrict__ h_out) {
    __shared__ __align__(16) unsigned short As[64 * 72];  // rows x k, stride 72 (pad)
    __shared__ __align__(16) unsigned short Bs[64 * 72];  // n    x k, stride 72

    const int tid  = threadIdx.x;
    const int lane = tid & 63;
    const int w    = tid >> 6;      // wave 0..3 -> rows w*16..
    const int q    = lane >> 4;     // quad 0..3
    const int mm   = lane & 15;
    const int row0 = blockIdx.x * 64;

    f32x4 acc[4];
#pragma unroll
    for (int nt = 0; nt < 4; nt++) acc[nt] = (f32x4){0.f, 0.f, 0.f, 0.f};

    for (int kt = 0; kt < 28; kt++) {
        // ---- stage B (Wt) : straight bf16 copy, 512 chunks of 8 elems ----
#pragma unroll
        for (int it = 0; it < 2; it++) {
            int i = tid + it * 256;
            int n = i >> 3, c = i & 7;
            const uint4* src = reinterpret_cast<const uint4*>(Wt + n * KPAD_ + kt * 64 + c * 8);
            *reinterpret_cast<uint4*>(&Bs[n * 72 + c * 8]) = *src;
        }
        // ---- stage A: load f32, convert to bf16 ----
#pragma unroll
        for (int it = 0; it < 2; it++) {
            int i = tid + it * 256;
            int m = i >> 3, c = i & 7;
            int row = row0 + m;
            float v[8];
            if (kt < 24) {
                const float4* s0 = reinterpret_cast<const float4*>(emb + (size_t)row * D_IN_ + kt * 64 + c * 8);
                float4 va = s0[0], vb = s0[1];
                v[0]=va.x; v[1]=va.y; v[2]=va.z; v[3]=va.w;
                v[4]=vb.x; v[5]=vb.y; v[6]=vb.z; v[7]=vb.w;
            } else {
                int kl = (kt - 24) * 64 + c * 8;
#pragma unroll
                for (int j = 0; j < 8; j++) {
                    int k2 = kl + j;
                    v[j] = (k2 < D_SC_) ? scores[(size_t)row * D_SC_ + k2] : 0.0f;
                }
            }
            __hip_bfloat16 bv[8];
#pragma unroll
            for (int j = 0; j < 8; j++) bv[j] = __float2bfloat16(v[j]);
            *reinterpret_cast<uint4*>(&As[m * 72 + c * 8]) = *reinterpret_cast<const uint4*>(bv);
        }
        __syncthreads();
#pragma unroll
        for (int ks = 0; ks < 2; ks++) {
            bf16x8 af = *reinterpret_cast<const bf16x8*>(&As[(w * 16 + mm) * 72 + ks * 32 + q * 8]);
#pragma unroll
            for (int nt = 0; nt < 4; nt++) {
                bf16x8 bfv = *reinterpret_cast<const bf16x8*>(&Bs[(nt * 16 + mm) * 72 + ks * 32 + q * 8]);
                acc[nt] = __builtin_amdgcn_mfma_f32_16x16x32_bf16(af, bfv, acc[nt], 0, 0, 0);
            }
        }
        __syncthreads();
    }

    // ---- epilogue: lane holds C[row = w*16 + q*4 + reg][n = nt*16 + mm] ----
    float binv[4], gl[4], bl[4];
#pragma unroll
    for (int nt = 0; nt < 4; nt++) {
        binv[nt] = b_in[nt * 16 + mm];
        gl[nt]   = ln_in_g[nt * 16 + mm];
        bl[nt]   = ln_in_b[nt * 16 + mm];
    }
#pragma unroll
    for (int nt = 0; nt < 4; nt++)
#pragma unroll
        for (int reg = 0; reg < 4; reg++) acc[nt][reg] += binv[nt];

    float sum[4], sq[4];
#pragma unroll
    for (int reg = 0; reg < 4; reg++) {
        sum[reg] = acc[0][reg] + acc[1][reg] + acc[2][reg] + acc[3][reg];
        sq[reg]  = acc[0][reg]*acc[0][reg] + acc[1][reg]*acc[1][reg]
                 + acc[2][reg]*acc[2][reg] + acc[3][reg]*acc[3][reg];
    }
#pragma unroll
    for (int m2 = 1; m2 <= 8; m2 <<= 1) {
#pragma unroll
        for (int reg = 0; reg < 4; reg++) {
            sum[reg] += __shfl_xor(sum[reg], m2);
            sq[reg]  += __shfl_xor(sq[reg], m2);
        }
    }
#pragma unroll
    for (int reg = 0; reg < 4; reg++) {
        float mu   = sum[reg] * 0.015625f;
        float var  = sq[reg] * 0.015625f - mu * mu;
        float rstd = rsqrtf(var + LN_EPS_);
        int row  = row0 + w * 16 + q * 4 + reg;
        int bidx = row / 12;
        int t    = row - bidx * 12;
        const float* mrow = meta + (size_t)bidx * 64;
        const float* prow = pos_enc + t * 64;
#pragma unroll
        for (int nt = 0; nt < 4; nt++) {
            int n = nt * 16 + mm;
            float x  = (acc[nt][reg] - mu) * rstd * gl[nt] + bl[nt];
            float ge = 0.5f * x * (1.0f + erff(x * 0.70710678118654752f));
            h_out[(size_t)row * 64 + n] = ge + mrow[n] + prow[n];
        }
    }
}

// ---------------- K2: per-b fused proj + fwd/bwd selective scan + merge + LN + out --------
__launch_bounds__(256)
__global__ void k2_ssm(const float* __restrict__ h_in,
                       const float* __restrict__ A_log_f, const float* __restrict__ Wp_f,
                       const float* __restrict__ bp_f, const float* __restrict__ D_f,
                       const float* __restrict__ A_log_b, const float* __restrict__ Wp_b,
                       const float* __restrict__ bp_b, const float* __restrict__ D_b,
                       const float* __restrict__ W_merge, const float* __restrict__ b_merge,
                       const float* __restrict__ ln_g, const float* __restrict__ ln_b,
                       const float* __restrict__ W_out, const float* __restrict__ b_out,
                       float* __restrict__ out) {
    __shared__ __align__(16) float h_s[T_ * 64];        // input rows (= residual)
    __shared__ __align__(16) float proj_s[2 * T_ * 80]; // [dir][scan t][80]
    __shared__ __align__(16) float y_s[2 * T_ * 64];    // [dir][scan t][64]
    __shared__ __align__(16) float g_s[T_ * 64];        // post-LN

    const int tid = threadIdx.x;
    const int b   = blockIdx.x;
    const float* hb = h_in + (size_t)b * T_ * 64;

    // phase 0: load h rows (768 f32)
    if (tid < 192)
        reinterpret_cast<float4*>(h_s)[tid] = reinterpret_cast<const float4*>(hb)[tid];
    __syncthreads();

    // phase 1: proj[dir][t][j] = x_dir[t] @ Wp + bp   (x_b[t] = h[11-t])
    if (tid < 160) {
        int dir = tid / 80, j = tid - dir * 80;
        const float* Wp = dir ? Wp_b : Wp_f;
        const float* bp = dir ? bp_b : bp_f;
        float acc[T_];
#pragma unroll
        for (int t = 0; t < T_; t++) acc[t] = bp[j];
        for (int kq = 0; kq < 16; kq++) {
            float w0 = Wp[(kq * 4 + 0) * 80 + j];
            float w1 = Wp[(kq * 4 + 1) * 80 + j];
            float w2 = Wp[(kq * 4 + 2) * 80 + j];
            float w3 = Wp[(kq * 4 + 3) * 80 + j];
#pragma unroll
            for (int t = 0; t < T_; t++) {
                int ts = dir ? (T_ - 1 - t) : t;
                float4 hv = *reinterpret_cast<const float4*>(&h_s[ts * 64 + kq * 4]);
                acc[t] += hv.x * w0 + hv.y * w1 + hv.z * w2 + hv.w * w3;
            }
        }
#pragma unroll
        for (int t = 0; t < T_; t++) proj_s[dir * T_ * 80 + t * 80 + j] = acc[t];
    }
    __syncthreads();

    // phase 2: selective scan, thread = (dir, d)
    if (tid < 128) {
        int dir = tid >> 6, d = tid & 63;
        const float* Alog = dir ? A_log_b : A_log_f;
        const float* Dp   = dir ? D_b : D_f;
        float4 a0 = *reinterpret_cast<const float4*>(Alog + d * 8);
        float4 a1 = *reinterpret_cast<const float4*>(Alog + d * 8 + 4);
        float a[8];
        a[0] = -__expf(a0.x); a[1] = -__expf(a0.y); a[2] = -__expf(a0.z); a[3] = -__expf(a0.w);
        a[4] = -__expf(a1.x); a[5] = -__expf(a1.y); a[6] = -__expf(a1.z); a[7] = -__expf(a1.w);
        float Dd = Dp[d];
        float st[8];
#pragma unroll
        for (int n = 0; n < 8; n++) st[n] = 0.0f;
        const float* ps = proj_s + dir * T_ * 80;
        for (int t = 0; t < T_; t++) {
            int ts = dir ? (T_ - 1 - t) : t;
            float x    = h_s[ts * 64 + d];
            float draw = ps[t * 80 + d];
            float delta = (draw > 20.0f) ? draw : log1pf(__expf(draw));
            float4 Bc0 = *reinterpret_cast<const float4*>(&ps[t * 80 + 64]);
            float4 Bc1 = *reinterpret_cast<const float4*>(&ps[t * 80 + 68]);
            float4 Cc0 = *reinterpret_cast<const float4*>(&ps[t * 80 + 72]);
            float4 Cc1 = *reinterpret_cast<const float4*>(&ps[t * 80 + 76]);
            float Bv[8] = {Bc0.x, Bc0.y, Bc0.z, Bc0.w, Bc1.x, Bc1.y, Bc1.z, Bc1.w};
            float Cv[8] = {Cc0.x, Cc0.y, Cc0.z, Cc0.w, Cc1.x, Cc1.y, Cc1.z, Cc1.w};
            float dx = delta * x;
            float y = 0.0f;
#pragma unroll
            for (int n = 0; n < 8; n++) {
                st[n] = __expf(delta * a[n]) * st[n] + dx * Bv[n];
                y += st[n] * Cv[n];
            }
            y_s[dir * T_ * 64 + t * 64 + d] = y + x * Dd;
        }
    }
    __syncthreads();

    // phase 3: merge (concat(y_f[t], y_b[logical t]) @ W_merge + b_merge) + residual + LN
    {
        int j = tid & 63, tg = tid >> 6;   // lanes = j exactly; each wave: t = tg, tg+4, tg+8
        float accm[3];
#pragma unroll
        for (int i = 0; i < 3; i++) accm[i] = b_merge[j];
        for (int kq = 0; kq < 32; kq++) {
            float w0 = W_merge[(kq * 4 + 0) * 64 + j];
            float w1 = W_merge[(kq * 4 + 1) * 64 + j];
            float w2 = W_merge[(kq * 4 + 2) * 64 + j];
            float w3 = W_merge[(kq * 4 + 3) * 64 + j];
#pragma unroll
            for (int i = 0; i < 3; i++) {
                int t = tg + i * 4;
                float4 yv;
                if (kq < 16) yv = *reinterpret_cast<const float4*>(&y_s[t * 64 + kq * 4]);
                else         yv = *reinterpret_cast<const float4*>(&y_s[T_ * 64 + (T_ - 1 - t) * 64 + (kq - 16) * 4]);
                accm[i] += yv.x * w0 + yv.y * w1 + yv.z * w2 + yv.w * w3;
            }
        }
#pragma unroll
        for (int i = 0; i < 3; i++) {
            int t = tg + i * 4;
            float r  = accm[i] + h_s[t * 64 + j];
            float s1 = r, s2 = r * r;
#pragma unroll
            for (int m2 = 1; m2 < 64; m2 <<= 1) { s1 += __shfl_xor(s1, m2); s2 += __shfl_xor(s2, m2); }
            float mu   = s1 * 0.015625f;
            float var  = s2 * 0.015625f - mu * mu;
            float rstd = rsqrtf(var + LN_EPS_);
            g_s[t * 64 + j] = (r - mu) * rstd * ln_g[j] + ln_b[j];
        }
    }
    __syncthreads();

    // phase 4: out[t][j] = g[t] @ W_out + b_out
    if (tid < NC_) {
        int j = tid;
        float acco[T_];
#pragma unroll
        for (int t = 0; t < T_; t++) acco[t] = b_out[j];
        for (int kq = 0; kq < 16; kq++) {
            float w0 = W_out[(kq * 4 + 0) * NC_ + j];
            float w1 = W_out[(kq * 4 + 1) * NC_ + j];
            float w2 = W_out[(kq * 4 + 2) * NC_ + j];
            float w3 = W_out[(kq * 4 + 3) * NC_ + j];
#pragma unroll
            for (int t = 0; t < T_; t++) {
                float4 gv = *reinterpret_cast<const float4*>(&g_s[t * 64 + kq * 4]);
                acco[t] += gv.x * w0 + gv.y * w1 + gv.z * w2 + gv.w * w3;
            }
        }
        float* ob = out + (size_t)b * T_ * NC_;
#pragma unroll
        for (int t = 0; t < T_; t++) ob[t * NC_ + j] = acco[t];
    }
}

extern "C" void kernel_launch(void* const* d_in, const int* in_sizes, int n_in,
                              void* d_out, int out_size, void* d_ws, size_t ws_size,
                              hipStream_t stream) {
    const float* emb      = (const float*)d_in[0];
    const float* scores   = (const float*)d_in[1];
    const int*   site_ids = (const int*)d_in[2];
    const int*   hours    = (const int*)d_in[3];
    const float* W_in     = (const float*)d_in[4];
    const float* b_in     = (const float*)d_in[5];
    const float* ln_in_g  = (const float*)d_in[6];
    const float* ln_in_b  = (const float*)d_in[7];
    const float* site_emb = (const float*)d_in[8];
    const float* hour_emb = (const float*)d_in[9];
    const float* W_meta   = (const float*)d_in[10];
    const float* b_meta   = (const float*)d_in[11];
    const float* pos_enc  = (const float*)d_in[12];
    const float* A_log_f  = (const float*)d_in[13];
    const float* Wp_f     = (const float*)d_in[14];
    const float* bp_f     = (const float*)d_in[15];
    const float* D_f      = (const float*)d_in[16];
    const float* A_log_b  = (const float*)d_in[17];
    const float* Wp_b     = (const float*)d_in[18];
    const float* bp_b     = (const float*)d_in[19];
    const float* D_b      = (const float*)d_in[20];
    const float* W_merge  = (const float*)d_in[21];
    const float* b_merge  = (const float*)d_in[22];
    const float* ln_g     = (const float*)d_in[23];
    const float* ln_b     = (const float*)d_in[24];
    const float* W_out    = (const float*)d_in[25];
    const float* b_out    = (const float*)d_in[26];

    char* ws = (char*)d_ws;
    unsigned short* Wt = (unsigned short*)ws;                 // 64*1792*2   = 229376 B
    float* meta = (float*)(ws + 229376);                      // 4096*64*4   = 1048576 B
    float* h_ws = (float*)(ws + 229376 + 1048576);            // 49152*64*4  = 12582912 B

    prep_w   <<<(64 * KPAD_ + 255) / 256, 256, 0, stream>>>(W_in, Wt);
    prep_meta<<<(B_ * 64 + 255) / 256, 256, 0, stream>>>(site_ids, hours, site_emb, hour_emb,
                                                         W_meta, b_meta, meta);
    k1_gemm  <<<NROW_ / 64, 256, 0, stream>>>(emb, scores, Wt, b_in, ln_in_g, ln_in_b,
                                              meta, pos_enc, h_ws);
    k2_ssm   <<<B_, 256, 0, stream>>>(h_ws, A_log_f, Wp_f, bp_f, D_f,
                                      A_log_b, Wp_b, bp_b, D_b,
                                      W_merge, b_merge, ln_g, ln_b, W_out, b_out,
                                      (float*)d_out);
}

// Round 3
// 562.133 us; speedup vs baseline: 1.1202x; 1.1202x over previous
//
#include <hip/hip_runtime.h>
#include <hip/hip_bf16.h>

#define D_IN_ 1536
#define D_SC_ 234
#define DM_   64
#define NC_   234
#define T_    12
#define NS_   20
#define B_    4096
#define NROW_ (B_ * T_)       // 49152
#define LN_EPS_ 1e-5f
#define PJS 164               // proj_s row stride (f32), 160+4 pad
#define RS_ 68                // r_s row stride

typedef __bf16 bf16x8 __attribute__((ext_vector_type(8)));
typedef float  f32x4  __attribute__((ext_vector_type(4)));

static __device__ __forceinline__ unsigned short f2bs(float f) {
    __hip_bfloat16 h = __float2bfloat16(f);
    return *reinterpret_cast<unsigned short*>(&h);
}
static __device__ __forceinline__ float bs2f(unsigned short u) {
    __hip_bfloat16 h = *reinterpret_cast<__hip_bfloat16*>(&u);
    return __bfloat162float(h);
}

// ============ prep: W_in [1770][64] -> Wt bf16 fragment-order ============
// layout (ushort idx): kt*4096 + ks*2048 + nt*512 + lane*8 + j
// lane=(q,mm): n = nt*16+mm, k = kt*64 + ks*32 + q*8 + j
__global__ void prep_w(const float* __restrict__ W_in, unsigned short* __restrict__ Wt) {
    int idx = blockIdx.x * 256 + threadIdx.x;
    if (idx >= 28 * 4096) return;
    int j = idx & 7, ln = (idx >> 3) & 63, nt = (idx >> 9) & 3, ks = (idx >> 11) & 1, kt = idx >> 12;
    int q = ln >> 4, mm = ln & 15;
    int n = nt * 16 + mm;
    int k = kt * 64 + ks * 32 + q * 8 + j;
    float v = (k < (D_IN_ + D_SC_)) ? W_in[k * 64 + n] : 0.0f;
    Wt[idx] = f2bs(v);
}

// ============ prep: Wp_f/Wp_b -> Wpt[20 tiles], W_merge -> Wmt[16], W_out -> Wot[30] ======
__global__ void prep_small(const float* __restrict__ Wp_f, const float* __restrict__ Wp_b,
                           const float* __restrict__ W_merge, const float* __restrict__ W_out,
                           unsigned short* __restrict__ Wpt, unsigned short* __restrict__ Wmt,
                           unsigned short* __restrict__ Wot) {
    int idx = blockIdx.x * 256 + threadIdx.x;
    if (idx >= 33792) return;
    int j = idx & 7, ln = (idx >> 3) & 63;
    int q = ln >> 4, mm = ln & 15;
    if (idx < 10240) {                       // Wpt: tile = nt*2+ks, K=64, N=160
        int tile = idx >> 9, nt = tile >> 1, ks = tile & 1;
        int n = nt * 16 + mm, k = ks * 32 + q * 8 + j;
        float v = (n >= 80) ? Wp_b[k * 80 + (n - 80)] : Wp_f[k * 80 + n];
        Wpt[idx] = f2bs(v);
    } else if (idx < 18432) {                // Wmt: tile = nt*4+ks, K=128, N=64
        int i2 = idx - 10240;
        int tile = i2 >> 9, nt = tile >> 2, ks = tile & 3;
        int n = nt * 16 + mm, k = ks * 32 + q * 8 + j;
        Wmt[i2] = f2bs(W_merge[k * 64 + n]);
    } else {                                 // Wot: tile = nt*2+ks, K=64, N=240 (pad 234)
        int i2 = idx - 18432;
        int tile = i2 >> 9, nt = tile >> 1, ks = tile & 1;
        int n = nt * 16 + mm, k = ks * 32 + q * 8 + j;
        Wot[i2] = f2bs((n < NC_) ? W_out[k * NC_ + n] : 0.0f);
    }
}

// ============ prep: meta[b][n] (stored bf16) ============
__global__ void prep_meta(const int* __restrict__ site_ids, const int* __restrict__ hours,
                          const float* __restrict__ site_emb, const float* __restrict__ hour_emb,
                          const float* __restrict__ W_meta, const float* __restrict__ b_meta,
                          unsigned short* __restrict__ meta_bf) {
    int idx = blockIdx.x * 256 + threadIdx.x;
    if (idx >= B_ * 64) return;
    int b = idx >> 6, n = idx & 63;
    int s = min(max(site_ids[b], 0), NS_ - 1);
    int h = min(max(hours[b], 0), 23);
    float acc = b_meta[n];
#pragma unroll
    for (int k = 0; k < 8; k++) acc += site_emb[s * 8 + k] * W_meta[k * 64 + n];
#pragma unroll
    for (int k = 0; k < 8; k++) acc += hour_emb[h * 8 + k] * W_meta[(8 + k) * 64 + n];
    meta_bf[idx] = f2bs(acc);
}

// ============ K1: streaming no-LDS MFMA GEMM + bias + LN + gelu + meta + pos ============
// one wave per 16-row strip; 3072 strips; 768 blocks of 4 waves
__launch_bounds__(256)
__global__ void k1_gemm(const float* __restrict__ emb, const float* __restrict__ scores,
                        const unsigned short* __restrict__ Wt,
                        const float* __restrict__ b_in, const float* __restrict__ ln_in_g,
                        const float* __restrict__ ln_in_b, const unsigned short* __restrict__ meta_bf,
                        const float* __restrict__ pos_enc, float* __restrict__ h_out) {
    const int tid  = threadIdx.x;
    const int lane = tid & 63;
    const int w    = tid >> 6;
    const int q    = lane >> 4;
    const int mm   = lane & 15;
    const int strip = blockIdx.x * 4 + w;
    const int row0  = strip * 16;

    const float* aptr = emb + (size_t)(row0 + mm) * D_IN_ + q * 8;
    const unsigned short* wptr = Wt + lane * 8;

    f32x4 acc[4];
#pragma unroll
    for (int nt = 0; nt < 4; nt++) acc[nt] = (f32x4){0.f, 0.f, 0.f, 0.f};

    float4 cur[4];   // [ks*2+half]: k = ks*32 + q*8 + half*4
#pragma unroll
    for (int h = 0; h < 4; h++)
        cur[h] = *reinterpret_cast<const float4*>(aptr + (h >> 1) * 32 + (h & 1) * 4);

    __align__(16) unsigned short av[2][8];

    for (int kt = 0; kt < 23; kt++) {
        float4 nxt[4];
#pragma unroll
        for (int h = 0; h < 4; h++)
            nxt[h] = *reinterpret_cast<const float4*>(aptr + (kt + 1) * 64 + (h >> 1) * 32 + (h & 1) * 4);
        bf16x8 bfr[2][4];
#pragma unroll
        for (int ks = 0; ks < 2; ks++)
#pragma unroll
            for (int nt = 0; nt < 4; nt++)
                bfr[ks][nt] = *reinterpret_cast<const bf16x8*>(wptr + kt * 4096 + ks * 2048 + nt * 512);
#pragma unroll
        for (int ks = 0; ks < 2; ks++) {
            const float* cf = reinterpret_cast<const float*>(&cur[ks * 2]);
#pragma unroll
            for (int j = 0; j < 8; j++) av[ks][j] = f2bs(cf[j]);
        }
#pragma unroll
        for (int ks = 0; ks < 2; ks++) {
            bf16x8 af = *reinterpret_cast<const bf16x8*>(av[ks]);
#pragma unroll
            for (int nt = 0; nt < 4; nt++)
                acc[nt] = __builtin_amdgcn_mfma_f32_16x16x32_bf16(af, bfr[ks][nt], acc[nt], 0, 0, 0);
        }
#pragma unroll
        for (int h = 0; h < 4; h++) cur[h] = nxt[h];
    }
    {   // kt = 23 (no prefetch)
        const int kt = 23;
        bf16x8 bfr[2][4];
#pragma unroll
        for (int ks = 0; ks < 2; ks++)
#pragma unroll
            for (int nt = 0; nt < 4; nt++)
                bfr[ks][nt] = *reinterpret_cast<const bf16x8*>(wptr + kt * 4096 + ks * 2048 + nt * 512);
#pragma unroll
        for (int ks = 0; ks < 2; ks++) {
            const float* cf = reinterpret_cast<const float*>(&cur[ks * 2]);
#pragma unroll
            for (int j = 0; j < 8; j++) av[ks][j] = f2bs(cf[j]);
        }
#pragma unroll
        for (int ks = 0; ks < 2; ks++) {
            bf16x8 af = *reinterpret_cast<const bf16x8*>(av[ks]);
#pragma unroll
            for (int nt = 0; nt < 4; nt++)
                acc[nt] = __builtin_amdgcn_mfma_f32_16x16x32_bf16(af, bfr[ks][nt], acc[nt], 0, 0, 0);
        }
    }
    // ---- scores tail: k 1536..1769 -> scores cols 0..233, f32 direct (float2-aligned) ----
    {
        const float* sp = scores + (size_t)(row0 + mm) * D_SC_;
#pragma unroll
        for (int kt2 = 0; kt2 < 4; kt2++) {
#pragma unroll
            for (int ks = 0; ks < 2; ks++) {
                int c0 = kt2 * 64 + ks * 32 + q * 8;
                __align__(16) unsigned short avt[8];
#pragma unroll
                for (int p = 0; p < 4; p++) {
                    int c = c0 + 2 * p;
                    float2 v;
                    if (c + 1 < D_SC_) v = *reinterpret_cast<const float2*>(sp + c);
                    else { v.x = 0.0f; v.y = 0.0f; }
                    avt[2 * p]     = f2bs(v.x);
                    avt[2 * p + 1] = f2bs(v.y);
                }
                bf16x8 af = *reinterpret_cast<const bf16x8*>(avt);
#pragma unroll
                for (int nt = 0; nt < 4; nt++) {
                    bf16x8 bv = *reinterpret_cast<const bf16x8*>(wptr + (24 + kt2) * 4096 + ks * 2048 + nt * 512);
                    acc[nt] = __builtin_amdgcn_mfma_f32_16x16x32_bf16(af, bv, acc[nt], 0, 0, 0);
                }
            }
        }
    }

    // ---- epilogue: lane holds C[row = q*4 + reg][n = nt*16 + mm] ----
    float binv[4], gl[4], bl[4];
#pragma unroll
    for (int nt = 0; nt < 4; nt++) {
        binv[nt] = b_in[nt * 16 + mm];
        gl[nt]   = ln_in_g[nt * 16 + mm];
        bl[nt]   = ln_in_b[nt * 16 + mm];
    }
#pragma unroll
    for (int nt = 0; nt < 4; nt++)
#pragma unroll
        for (int reg = 0; reg < 4; reg++) acc[nt][reg] += binv[nt];

    float sum[4], sq[4];
#pragma unroll
    for (int reg = 0; reg < 4; reg++) {
        sum[reg] = acc[0][reg] + acc[1][reg] + acc[2][reg] + acc[3][reg];
        sq[reg]  = acc[0][reg]*acc[0][reg] + acc[1][reg]*acc[1][reg]
                 + acc[2][reg]*acc[2][reg] + acc[3][reg]*acc[3][reg];
    }
#pragma unroll
    for (int m2 = 1; m2 <= 8; m2 <<= 1) {
#pragma unroll
        for (int reg = 0; reg < 4; reg++) {
            sum[reg] += __shfl_xor(sum[reg], m2);
            sq[reg]  += __shfl_xor(sq[reg], m2);
        }
    }
#pragma unroll
    for (int reg = 0; reg < 4; reg++) {
        float mu   = sum[reg] * 0.015625f;
        float var  = sq[reg] * 0.015625f - mu * mu;
        float rstd = rsqrtf(var + LN_EPS_);
        int row  = row0 + q * 4 + reg;
        int bidx = row / 12;
        int t    = row - bidx * 12;
        const unsigned short* mrow = meta_bf + (size_t)bidx * 64;
        const float* prow = pos_enc + t * 64;
#pragma unroll
        for (int nt = 0; nt < 4; nt++) {
            int n = nt * 16 + mm;
            float x  = (acc[nt][reg] - mu) * rstd * gl[nt] + bl[nt];
            float ge = 0.5f * x * (1.0f + erff(x * 0.70710678118654752f));
            h_out[(size_t)row * 64 + n] = ge + bs2f(mrow[n]) + prow[n];
        }
    }
}

// ============ K2: per-b fused MFMA proj + scan + MFMA merge + LN + MFMA out ============
__launch_bounds__(256)
__global__ void k2_ssm(const float* __restrict__ h_in,
                       const float* __restrict__ A_log_f, const float* __restrict__ bp_f,
                       const float* __restrict__ D_f,
                       const float* __restrict__ A_log_b, const float* __restrict__ bp_b,
                       const float* __restrict__ D_b,
                       const unsigned short* __restrict__ Wpt, const unsigned short* __restrict__ Wmt,
                       const unsigned short* __restrict__ Wot,
                       const float* __restrict__ b_merge, const float* __restrict__ ln_g,
                       const float* __restrict__ ln_b, const float* __restrict__ b_out,
                       float* __restrict__ out) {
    __shared__ float h_s[T_ * 64];                         // residual + scan x (f32)
    __shared__ __align__(16) unsigned short hb_s[1024];    // h bf16, frag-order (2 ks chunks)
    __shared__ float proj_s[T_ * PJS];                     // proj rows (source-row order)
    __shared__ __align__(16) unsigned short yb_s[2048];    // y concat bf16 frag-order (4 ks)
    __shared__ float r_s[T_ * RS_];                        // merge+residual pre-LN
    __shared__ __align__(16) unsigned short gb_s[1024];    // post-LN bf16 frag-order (2 ks)

    const int tid  = threadIdx.x;
    const int lane = tid & 63;
    const int w    = tid >> 6;
    const int q    = lane >> 4;
    const int mm   = lane & 15;
    const int b    = blockIdx.x;

    // ---- phase 0: load h rows, convert to frag-order bf16 ----
    if (tid < 192) {
        float4 hv = reinterpret_cast<const float4*>(h_in + (size_t)b * (T_ * 64))[tid];
        *reinterpret_cast<float4*>(&h_s[tid * 4]) = hv;
        int m = tid >> 4, c0 = (tid & 15) * 4;
        int base = (c0 >> 5) * 512 + (((c0 >> 3) & 3) * 16 + m) * 8 + (c0 & 7);
        hb_s[base + 0] = f2bs(hv.x);
        hb_s[base + 1] = f2bs(hv.y);
        hb_s[base + 2] = f2bs(hv.z);
        hb_s[base + 3] = f2bs(hv.w);
    }
    __syncthreads();

    // ---- phase 1: proj = h @ [Wp_f | Wp_b] + bp  (M=16, N=160, K=64) ----
    {
        bf16x8 a0 = *reinterpret_cast<const bf16x8*>(&hb_s[lane * 8]);
        bf16x8 a1 = *reinterpret_cast<const bf16x8*>(&hb_s[512 + lane * 8]);
#pragma unroll
        for (int i = 0; i < 3; i++) {
            int nt = w + i * 4;
            if (nt < 10) {
                bf16x8 b0 = *reinterpret_cast<const bf16x8*>(Wpt + (nt * 2 + 0) * 512 + lane * 8);
                bf16x8 b1 = *reinterpret_cast<const bf16x8*>(Wpt + (nt * 2 + 1) * 512 + lane * 8);
                f32x4 c = (f32x4){0.f, 0.f, 0.f, 0.f};
                c = __builtin_amdgcn_mfma_f32_16x16x32_bf16(a0, b0, c, 0, 0, 0);
                c = __builtin_amdgcn_mfma_f32_16x16x32_bf16(a1, b1, c, 0, 0, 0);
                int n = nt * 16 + mm;
                float bpv = (n >= 80) ? bp_b[n - 80] : bp_f[n];
                if (q < 3) {
#pragma unroll
                    for (int reg = 0; reg < 4; reg++)
                        proj_s[(q * 4 + reg) * PJS + n] = c[reg] + bpv;
                }
            }
        }
    }
    __syncthreads();

    // ---- phase 2: selective scan, thread = (dir, d) ----
    if (tid < 128) {
        int dir = tid >> 6, d = tid & 63;
        const float* Alog = dir ? A_log_b : A_log_f;
        const float* Dp   = dir ? D_b : D_f;
        float a[8];
#pragma unroll
        for (int n = 0; n < 8; n++) a[n] = -__expf(Alog[d * 8 + n]);
        float Dd = Dp[d];
        float st[8];
#pragma unroll
        for (int n = 0; n < 8; n++) st[n] = 0.0f;
        for (int t = 0; t < T_; t++) {
            int ts = dir ? (T_ - 1 - t) : t;
            float x    = h_s[ts * 64 + d];
            float draw = proj_s[ts * PJS + dir * 80 + d];
            float delta = (draw > 20.0f) ? draw : log1pf(__expf(draw));
            const float* pb = &proj_s[ts * PJS + dir * 80 + 64];
            float4 B0 = *reinterpret_cast<const float4*>(pb);
            float4 B1 = *reinterpret_cast<const float4*>(pb + 4);
            float4 C0 = *reinterpret_cast<const float4*>(pb + 8);
            float4 C1 = *reinterpret_cast<const float4*>(pb + 12);
            float Bv[8] = {B0.x, B0.y, B0.z, B0.w, B1.x, B1.y, B1.z, B1.w};
            float Cv[8] = {C0.x, C0.y, C0.z, C0.w, C1.x, C1.y, C1.z, C1.w};
            float dx = delta * x;
            float y = 0.0f;
#pragma unroll
            for (int n = 0; n < 8; n++) {
                st[n] = __expf(delta * a[n]) * st[n] + dx * Bv[n];
                y += st[n] * Cv[n];
            }
            float yv = y + x * Dd;
            int kk = dir * 64 + d;  // concat col; logical row = ts
            yb_s[(kk >> 5) * 512 + (((kk >> 3) & 3) * 16 + ts) * 8 + (kk & 7)] = f2bs(yv);
        }
    }
    __syncthreads();

    // ---- phase 3: merge = ycat @ W_merge + b_merge + residual  (M=16, N=64, K=128) ----
    {
        int nt = w;  // 4 tiles, one per wave
        f32x4 c = (f32x4){0.f, 0.f, 0.f, 0.f};
#pragma unroll
        for (int ks = 0; ks < 4; ks++) {
            bf16x8 A = *reinterpret_cast<const bf16x8*>(&yb_s[ks * 512 + lane * 8]);
            bf16x8 Bm = *reinterpret_cast<const bf16x8*>(Wmt + (nt * 4 + ks) * 512 + lane * 8);
            c = __builtin_amdgcn_mfma_f32_16x16x32_bf16(A, Bm, c, 0, 0, 0);
        }
        int n = nt * 16 + mm;
        float bm = b_merge[n];
        if (q < 3) {
#pragma unroll
            for (int reg = 0; reg < 4; reg++) {
                int t = q * 4 + reg;
                r_s[t * RS_ + n] = c[reg] + bm + h_s[t * 64 + n];
            }
        }
    }
    __syncthreads();

    // ---- phase 3b: LN over rows (wave per t-group, lane = col) ----
    {
        int j = lane;
#pragma unroll
        for (int i = 0; i < 3; i++) {
            int t = w + i * 4;
            float r  = r_s[t * RS_ + j];
            float s1 = r, s2 = r * r;
#pragma unroll
            for (int m2 = 1; m2 < 64; m2 <<= 1) { s1 += __shfl_xor(s1, m2); s2 += __shfl_xor(s2, m2); }
            float mu   = s1 * 0.015625f;
            float var  = s2 * 0.015625f - mu * mu;
            float rstd = rsqrtf(var + LN_EPS_);
            float g = (r - mu) * rstd * ln_g[j] + ln_b[j];
            gb_s[(j >> 5) * 512 + (((j >> 3) & 3) * 16 + t) * 8 + (j & 7)] = f2bs(g);
        }
    }
    __syncthreads();

    // ---- phase 4: out = g @ W_out + b_out  (M=16, N=240 pad, K=64) ----
    {
        bf16x8 a0 = *reinterpret_cast<const bf16x8*>(&gb_s[lane * 8]);
        bf16x8 a1 = *reinterpret_cast<const bf16x8*>(&gb_s[512 + lane * 8]);
#pragma unroll
        for (int i = 0; i < 4; i++) {
            int nt = w + i * 4;
            if (nt < 15) {
                bf16x8 b0 = *reinterpret_cast<const bf16x8*>(Wot + (nt * 2 + 0) * 512 + lane * 8);
                bf16x8 b1 = *reinterpret_cast<const bf16x8*>(Wot + (nt * 2 + 1) * 512 + lane * 8);
                f32x4 c = (f32x4){0.f, 0.f, 0.f, 0.f};
                c = __builtin_amdgcn_mfma_f32_16x16x32_bf16(a0, b0, c, 0, 0, 0);
                c = __builtin_amdgcn_mfma_f32_16x16x32_bf16(a1, b1, c, 0, 0, 0);
                int n = nt * 16 + mm;
                if (n < NC_) {
                    float bo = b_out[n];
                    if (q < 3) {
#pragma unroll
                        for (int reg = 0; reg < 4; reg++) {
                            int t = q * 4 + reg;
                            out[(size_t)b * (T_ * NC_) + t * NC_ + n] = c[reg] + bo;
                        }
                    }
                }
            }
        }
    }
}

extern "C" void kernel_launch(void* const* d_in, const int* in_sizes, int n_in,
                              void* d_out, int out_size, void* d_ws, size_t ws_size,
                              hipStream_t stream) {
    const float* emb      = (const float*)d_in[0];
    const float* scores   = (const float*)d_in[1];
    const int*   site_ids = (const int*)d_in[2];
    const int*   hours    = (const int*)d_in[3];
    const float* W_in     = (const float*)d_in[4];
    const float* b_in     = (const float*)d_in[5];
    const float* ln_in_g  = (const float*)d_in[6];
    const float* ln_in_b  = (const float*)d_in[7];
    const float* site_emb = (const float*)d_in[8];
    const float* hour_emb = (const float*)d_in[9];
    const float* W_meta   = (const float*)d_in[10];
    const float* b_meta   = (const float*)d_in[11];
    const float* pos_enc  = (const float*)d_in[12];
    const float* A_log_f  = (const float*)d_in[13];
    const float* Wp_f     = (const float*)d_in[14];
    const float* bp_f     = (const float*)d_in[15];
    const float* D_f      = (const float*)d_in[16];
    const float* A_log_b  = (const float*)d_in[17];
    const float* Wp_b     = (const float*)d_in[18];
    const float* bp_b     = (const float*)d_in[19];
    const float* D_b      = (const float*)d_in[20];
    const float* W_merge  = (const float*)d_in[21];
    const float* b_merge  = (const float*)d_in[22];
    const float* ln_g     = (const float*)d_in[23];
    const float* ln_b     = (const float*)d_in[24];
    const float* W_out    = (const float*)d_in[25];
    const float* b_out    = (const float*)d_in[26];

    // ws budget: stay under 13,860,864 B (round-1-proven safe footprint)
    char* ws = (char*)d_ws;
    unsigned short* Wt      = (unsigned short*)(ws + 0);         //   229,376 B
    unsigned short* meta_bf = (unsigned short*)(ws + 229376);    //   524,288 B
    unsigned short* Wpt     = (unsigned short*)(ws + 753664);    //    20,480 B
    unsigned short* Wmt     = (unsigned short*)(ws + 774144);    //    16,384 B
    unsigned short* Wot     = (unsigned short*)(ws + 790528);    //    30,720 B
    float*          h_ws    = (float*)(ws + 821248);             // 12,582,912 B -> ends 13,404,160

    prep_w      <<<448, 256, 0, stream>>>(W_in, Wt);
    prep_small  <<<132, 256, 0, stream>>>(Wp_f, Wp_b, W_merge, W_out, Wpt, Wmt, Wot);
    prep_meta   <<<1024, 256, 0, stream>>>(site_ids, hours, site_emb, hour_emb, W_meta, b_meta, meta_bf);
    k1_gemm     <<<768, 256, 0, stream>>>(emb, scores, Wt, b_in, ln_in_g, ln_in_b, meta_bf, pos_enc, h_ws);
    k2_ssm      <<<4096, 256, 0, stream>>>(h_ws, A_log_f, bp_f, D_f, A_log_b, bp_b, D_b,
                                           Wpt, Wmt, Wot, b_merge, ln_g, ln_b, b_out,
                                           (float*)d_out);
}